// Round 3
// baseline (750.986 us; speedup 1.0000x reference)
//
#include <hip/hip_runtime.h>
#include <math.h>

#define N0 1000000
#define N1 40960
#define N2 4096
#define E1 1024000
#define E2 40960
#define IN_C 100
#define HID 256
#define OUT_C 47
#define S1 128   // ELL stride layer1 (deg ~Poisson(25))
#define S2 64    // ELL stride layer2 (deg ~Poisson(10))

// ---------------------------------------------------------------------------
// Single-pass ELL build, 2 edges per thread (int2 loads).
// ---------------------------------------------------------------------------
__global__ __launch_bounds__(256) void build_kernel(
    const int* __restrict__ src1, const int* __restrict__ dst1,
    const int* __restrict__ src2, const int* __restrict__ dst2,
    int* __restrict__ deg1, int* __restrict__ ell1,
    int* __restrict__ deg2, int* __restrict__ ell2) {
    int gid = blockIdx.x * 256 + threadIdx.x;
    if (gid < E1 / 2) {
        int2 s = ((const int2*)src1)[gid];
        int2 d = ((const int2*)dst1)[gid];
        int slot0 = atomicAdd(&deg1[d.x], 1);
        if (slot0 < S1) ell1[d.x * S1 + slot0] = s.x;
        int slot1 = atomicAdd(&deg1[d.y], 1);
        if (slot1 < S1) ell1[d.y * S1 + slot1] = s.y;
    } else {
        int p = gid - E1 / 2;   // < E2/2 by grid sizing
        int2 s = ((const int2*)src2)[p];
        int2 d = ((const int2*)dst2)[p];
        int slot0 = atomicAdd(&deg2[d.x], 1);
        if (slot0 < S2) ell2[d.x * S2 + slot0] = s.x;
        int slot1 = atomicAdd(&deg2[d.y], 1);
        if (slot1 < S2) ell2[d.y * S2 + slot1] = s.y;
    }
}

// ---------------------------------------------------------------------------
// Fused layer 1: aggregate 32 rows into LDS (interleaved with self rows),
// then GEMM + bias + relu.  h[i][j] = relu(agg[i].W1l[:,j] + b1l[j] + x[i].W1r[:,j])
// Block: 256 thr = 4 waves; wave aggregates 8 rows; GEMM 8 rows x 4 cols/thread.
// Phase mix across blocks on a CU overlaps gather (VMEM) with GEMM (VALU).
// ---------------------------------------------------------------------------
__global__ __launch_bounds__(256) void fused1_kernel(
    const float* __restrict__ x, const int* __restrict__ ell1,
    const int* __restrict__ deg1,
    const float* __restrict__ W1l, const float* __restrict__ b1l,
    const float* __restrict__ W1r, float* __restrict__ h) {
    __shared__ float axs[32][2 * IN_C];   // [r][2k]=agg, [2k+1]=x_self ; 25.6 KB
    int tid = threadIdx.x;
    int lane = tid & 63;
    int w = tid >> 6;
    int i0 = blockIdx.x * 32;

    // self rows -> odd slots (cooperative, coalesced-ish)
    for (int idx = tid; idx < 32 * IN_C; idx += 256) {
        int r = idx / IN_C;
        int k = idx - r * IN_C;
        axs[r][2 * k + 1] = x[(i0 + r) * IN_C + k];
    }

    // aggregate: wave w owns rows w*8 .. w*8+7; lanes over channels
    int c1 = 64 + lane;
    int c1m = (c1 < IN_C) ? c1 : 0;   // clamped addr; lanes >=36 discard
    #pragma unroll 1
    for (int rr = 0; rr < 8; ++rr) {
        int r = w * 8 + rr;
        int row = i0 + r;
        int nd = deg1[row];
        int n = (nd < S1) ? nd : S1;
        const int* rp = ell1 + row * S1;
        float a0 = 0.f, a1 = 0.f, b0 = 0.f, b1 = 0.f;
        int e = 0;
        for (; e + 3 < n; e += 4) {
            int s0 = rp[e], s1 = rp[e + 1], s2 = rp[e + 2], s3 = rp[e + 3];
            const float* p0 = x + s0 * IN_C;
            const float* p1 = x + s1 * IN_C;
            const float* p2 = x + s2 * IN_C;
            const float* p3 = x + s3 * IN_C;
            float v0 = p0[lane], v1 = p1[lane], v2 = p2[lane], v3 = p3[lane];
            float w0 = p0[c1m], w1 = p1[c1m], w2 = p2[c1m], w3 = p3[c1m];
            a0 += v0 + v1; b0 += v2 + v3;
            a1 += w0 + w1; b1 += w2 + w3;
        }
        for (; e < n; ++e) {
            int s = rp[e];
            const float* p = x + s * IN_C;
            a0 += p[lane];
            a1 += p[c1m];
        }
        a0 += b0; a1 += b1;
        float inv = 1.0f / (float)(nd > 0 ? nd : 1);
        axs[r][2 * lane] = a0 * inv;
        if (c1 < IN_C) axs[r][2 * c1] = a1 * inv;
    }
    __syncthreads();

    // GEMM phase
    int jq = lane;
    int rgrp = w;
    int j4 = jq * 4;
    const float4* wl = (const float4*)(W1l + j4);
    const float4* wr = (const float4*)(W1r + j4);
    const float4* ax4 = (const float4*)(&axs[rgrp * 8][0]);  // row stride 50 float4

    float acc[8][4];
    #pragma unroll
    for (int r = 0; r < 8; ++r)
        #pragma unroll
        for (int c = 0; c < 4; ++c) acc[r][c] = 0.f;

    for (int k = 0; k < IN_C; k += 2) {
        float4 wl0 = wl[k * 64];
        float4 wr0 = wr[k * 64];
        float4 wl1 = wl[(k + 1) * 64];
        float4 wr1 = wr[(k + 1) * 64];
        int kh = k >> 1;
        #pragma unroll
        for (int r = 0; r < 8; ++r) {
            float4 v = ax4[r * 50 + kh];  // (a_k, x_k, a_{k+1}, x_{k+1}) wave-broadcast
            acc[r][0] += v.x * wl0.x + v.y * wr0.x + v.z * wl1.x + v.w * wr1.x;
            acc[r][1] += v.x * wl0.y + v.y * wr0.y + v.z * wl1.y + v.w * wr1.y;
            acc[r][2] += v.x * wl0.z + v.y * wr0.z + v.z * wl1.z + v.w * wr1.z;
            acc[r][3] += v.x * wl0.w + v.y * wr0.w + v.z * wl1.w + v.w * wr1.w;
        }
    }

    float4 b = *(const float4*)(b1l + j4);
    #pragma unroll
    for (int r = 0; r < 8; ++r) {
        int row = i0 + rgrp * 8 + r;
        float4 o;
        o.x = fmaxf(acc[r][0] + b.x, 0.f);
        o.y = fmaxf(acc[r][1] + b.y, 0.f);
        o.z = fmaxf(acc[r][2] + b.z, 0.f);
        o.w = fmaxf(acc[r][3] + b.w, 0.f);
        *(float4*)(h + row * HID + j4) = o;
    }
}

// ---------------------------------------------------------------------------
// Fused layer 2: per-wave aggregation (float4/lane over 256ch) -> LDS ->
// GEMM (lanes 0..46 = output cols) + bias + wave-level log_softmax.
// ---------------------------------------------------------------------------
__global__ __launch_bounds__(256) void l2_fused_kernel(
    const float* __restrict__ h, const int* __restrict__ ell2,
    const int* __restrict__ deg2,
    const float* __restrict__ W2l, const float* __restrict__ b2l,
    const float* __restrict__ W2r, float* __restrict__ out) {
    __shared__ float sa[4][HID];
    __shared__ float sh_[4][HID];
    int w = threadIdx.x >> 6;
    int lane = threadIdx.x & 63;
    int row = (blockIdx.x << 2) + w;

    int nd = deg2[row];
    int n = (nd < S2) ? nd : S2;
    const int* rp = ell2 + row * S2;
    float4 acc4 = {0.f, 0.f, 0.f, 0.f};
    int e = 0;
    for (; e + 1 < n; e += 2) {
        int s0 = rp[e], s1 = rp[e + 1];
        float4 v0 = ((const float4*)(h + s0 * HID))[lane];
        float4 v1 = ((const float4*)(h + s1 * HID))[lane];
        acc4.x += v0.x + v1.x; acc4.y += v0.y + v1.y;
        acc4.z += v0.z + v1.z; acc4.w += v0.w + v1.w;
    }
    if (e < n) {
        int s0 = rp[e];
        float4 v0 = ((const float4*)(h + s0 * HID))[lane];
        acc4.x += v0.x; acc4.y += v0.y; acc4.z += v0.z; acc4.w += v0.w;
    }
    float inv = 1.0f / (float)(nd > 0 ? nd : 1);
    float4 am = {acc4.x * inv, acc4.y * inv, acc4.z * inv, acc4.w * inv};
    ((float4*)&sa[w][0])[lane] = am;
    ((float4*)&sh_[w][0])[lane] = ((const float4*)(h + row * HID))[lane];
    __syncthreads();

    int j = lane;
    int jj = (j < OUT_C) ? j : (OUT_C - 1);
    float acc = 0.f;
    for (int k = 0; k < HID; k += 4) {
        float4 av = *(const float4*)&sa[w][k];   // same-addr broadcast
        float4 hv = *(const float4*)&sh_[w][k];
        acc += av.x * W2l[(k + 0) * OUT_C + jj] + hv.x * W2r[(k + 0) * OUT_C + jj];
        acc += av.y * W2l[(k + 1) * OUT_C + jj] + hv.y * W2r[(k + 1) * OUT_C + jj];
        acc += av.z * W2l[(k + 2) * OUT_C + jj] + hv.z * W2r[(k + 2) * OUT_C + jj];
        acc += av.w * W2l[(k + 3) * OUT_C + jj] + hv.w * W2r[(k + 3) * OUT_C + jj];
    }
    float v = acc + b2l[jj];
    float vm = (j < OUT_C) ? v : -__builtin_huge_valf();
    #pragma unroll
    for (int s = 32; s > 0; s >>= 1) vm = fmaxf(vm, __shfl_xor(vm, s));
    float ex = (j < OUT_C) ? __expf(v - vm) : 0.f;
    #pragma unroll
    for (int s = 32; s > 0; s >>= 1) ex += __shfl_xor(ex, s);
    if (j < OUT_C) out[row * OUT_C + j] = v - vm - __logf(ex);
}

// ---------------------------------------------------------------------------
extern "C" void kernel_launch(void* const* d_in, const int* in_sizes, int n_in,
                              void* d_out, int out_size, void* d_ws, size_t ws_size,
                              hipStream_t stream) {
    const float* x   = (const float*)d_in[0];
    const float* W1l = (const float*)d_in[1];
    const float* b1l = (const float*)d_in[2];
    const float* W1r = (const float*)d_in[3];
    const float* W2l = (const float*)d_in[4];
    const float* b2l = (const float*)d_in[5];
    const float* W2r = (const float*)d_in[6];
    const int* src1  = (const int*)d_in[7];
    const int* dst1  = (const int*)d_in[8];
    const int* src2  = (const int*)d_in[9];
    const int* dst2  = (const int*)d_in[10];
    float* out = (float*)d_out;

    char* ws = (char*)d_ws;
    size_t off = 0;
    auto alloc = [&](size_t bytes) {
        off = (off + 255) & ~(size_t)255;
        void* p = ws + off;
        off += bytes;
        return p;
    };

    int* deg1 = (int*)alloc(N1 * sizeof(int));       // contiguous with deg2
    int* deg2 = (int*)alloc(N2 * sizeof(int));
    int* ell1 = (int*)alloc((size_t)N1 * S1 * sizeof(int));
    int* ell2 = (int*)alloc((size_t)N2 * S2 * sizeof(int));
    float* h  = (float*)alloc((size_t)N1 * HID * sizeof(float));

    hipMemsetAsync(deg1, 0, (N1 + N2) * sizeof(int), stream);

    build_kernel<<<(E1 / 2 + E2 / 2) / 256, 256, 0, stream>>>(
        src1, dst1, src2, dst2, deg1, ell1, deg2, ell2);
    fused1_kernel<<<N1 / 32, 256, 0, stream>>>(x, ell1, deg1, W1l, b1l, W1r, h);
    l2_fused_kernel<<<N2 / 4, 256, 0, stream>>>(h, ell2, deg2, W2l, b2l, W2r, out);
}

// Round 4
// 710.063 us; speedup vs baseline: 1.0576x; 1.0576x over previous
//
#include <hip/hip_runtime.h>
#include <math.h>

#define N0 1000000
#define N1 40960
#define N2 4096
#define E1 1024000
#define E2 40960
#define IN_C 100
#define HID 256
#define OUT_C 47
#define S1 128   // ELL stride layer1 (deg ~Poisson(25))
#define S2 64    // ELL stride layer2 (deg ~Poisson(10))

// ---------------------------------------------------------------------------
// Single-pass ELL build, 2 edges per thread (int2 loads).
// ---------------------------------------------------------------------------
__global__ __launch_bounds__(256) void build_kernel(
    const int* __restrict__ src1, const int* __restrict__ dst1,
    const int* __restrict__ src2, const int* __restrict__ dst2,
    int* __restrict__ deg1, int* __restrict__ ell1,
    int* __restrict__ deg2, int* __restrict__ ell2) {
    int gid = blockIdx.x * 256 + threadIdx.x;
    if (gid < E1 / 2) {
        int2 s = ((const int2*)src1)[gid];
        int2 d = ((const int2*)dst1)[gid];
        int slot0 = atomicAdd(&deg1[d.x], 1);
        if (slot0 < S1) ell1[d.x * S1 + slot0] = s.x;
        int slot1 = atomicAdd(&deg1[d.y], 1);
        if (slot1 < S1) ell1[d.y * S1 + slot1] = s.y;
    } else {
        int p = gid - E1 / 2;   // < E2/2 by grid sizing
        int2 s = ((const int2*)src2)[p];
        int2 d = ((const int2*)dst2)[p];
        int slot0 = atomicAdd(&deg2[d.x], 1);
        if (slot0 < S2) ell2[d.x * S2 + slot0] = s.x;
        int slot1 = atomicAdd(&deg2[d.y], 1);
        if (slot1 < S2) ell2[d.y * S2 + slot1] = s.y;
    }
}

// ---------------------------------------------------------------------------
// Layer 1 mean-aggregation: one wave per dst node. Row = 50 float2 exactly;
// lane l (l<50) reads float2 #l of each source row -> ONE coalesced 400B
// load per edge. 8-edge unroll -> 8 independent loads in flight per wave.
// ---------------------------------------------------------------------------
__global__ __launch_bounds__(256) void agg1_kernel(
    const float* __restrict__ x, const int* __restrict__ ell1,
    const int* __restrict__ deg1, float* __restrict__ aggm1) {
    int d = (blockIdx.x << 2) + (threadIdx.x >> 6);
    int lane = threadIdx.x & 63;
    int l2 = (lane < 50) ? lane : 49;   // clamped; lanes 50..63 discard
    int nd = deg1[d];
    int n = (nd < S1) ? nd : S1;
    const int* rp = ell1 + d * S1;

    float x0 = 0.f, y0 = 0.f, x1 = 0.f, y1 = 0.f;
    float x2 = 0.f, y2 = 0.f, x3 = 0.f, y3 = 0.f;
    int e = 0;
    for (; e + 7 < n; e += 8) {
        int s0 = rp[e],     s1 = rp[e + 1], s2 = rp[e + 2], s3 = rp[e + 3];
        int s4 = rp[e + 4], s5 = rp[e + 5], s6 = rp[e + 6], s7 = rp[e + 7];
        float2 v0 = ((const float2*)(x + s0 * IN_C))[l2];
        float2 v1 = ((const float2*)(x + s1 * IN_C))[l2];
        float2 v2 = ((const float2*)(x + s2 * IN_C))[l2];
        float2 v3 = ((const float2*)(x + s3 * IN_C))[l2];
        float2 v4 = ((const float2*)(x + s4 * IN_C))[l2];
        float2 v5 = ((const float2*)(x + s5 * IN_C))[l2];
        float2 v6 = ((const float2*)(x + s6 * IN_C))[l2];
        float2 v7 = ((const float2*)(x + s7 * IN_C))[l2];
        x0 += v0.x + v4.x; y0 += v0.y + v4.y;
        x1 += v1.x + v5.x; y1 += v1.y + v5.y;
        x2 += v2.x + v6.x; y2 += v2.y + v6.y;
        x3 += v3.x + v7.x; y3 += v3.y + v7.y;
    }
    for (; e + 1 < n; e += 2) {
        int s0 = rp[e], s1 = rp[e + 1];
        float2 v0 = ((const float2*)(x + s0 * IN_C))[l2];
        float2 v1 = ((const float2*)(x + s1 * IN_C))[l2];
        x0 += v0.x; y0 += v0.y;
        x1 += v1.x; y1 += v1.y;
    }
    if (e < n) {
        float2 v0 = ((const float2*)(x + rp[e] * IN_C))[l2];
        x0 += v0.x; y0 += v0.y;
    }
    float sx = (x0 + x1) + (x2 + x3);
    float sy = (y0 + y1) + (y2 + y3);
    float inv = 1.0f / (float)(nd > 0 ? nd : 1);
    if (lane < 50) {
        float2 o = {sx * inv, sy * inv};
        ((float2*)(aggm1 + d * IN_C))[lane] = o;
    }
}

// ---------------------------------------------------------------------------
// Layer 1 GEMM + bias + relu:
//   h[i][j] = relu(aggm1[i] . W1l[:,j] + b1l[j] + x[i] . W1r[:,j])
// Block: 32 rows x 256 cols; thread: 8 rows x 4 cols.
// ---------------------------------------------------------------------------
__global__ __launch_bounds__(256) void gemm1_kernel(
    const float* __restrict__ aggm1, const float* __restrict__ x,
    const float* __restrict__ W1l, const float* __restrict__ b1l,
    const float* __restrict__ W1r, float* __restrict__ h) {
    __shared__ float axs[32][2 * IN_C];   // interleaved (a,x); 25.6 KB
    int tid = threadIdx.x;
    int i0 = blockIdx.x * 32;
    for (int idx = tid; idx < 32 * IN_C; idx += 256) {
        int r = idx / IN_C;
        int k = idx - r * IN_C;
        int row = i0 + r;
        axs[r][2 * k]     = aggm1[row * IN_C + k];
        axs[r][2 * k + 1] = x[row * IN_C + k];
    }
    __syncthreads();

    int jq = tid & 63;
    int rgrp = tid >> 6;
    int j4 = jq * 4;
    const float4* wl = (const float4*)(W1l + j4);
    const float4* wr = (const float4*)(W1r + j4);
    const float4* ax4 = (const float4*)(&axs[rgrp * 8][0]);  // row stride 50 float4

    float acc[8][4];
    #pragma unroll
    for (int r = 0; r < 8; ++r)
        #pragma unroll
        for (int c = 0; c < 4; ++c) acc[r][c] = 0.f;

    for (int k = 0; k < IN_C; k += 2) {
        float4 wl0 = wl[k * 64];
        float4 wr0 = wr[k * 64];
        float4 wl1 = wl[(k + 1) * 64];
        float4 wr1 = wr[(k + 1) * 64];
        int kh = k >> 1;
        #pragma unroll
        for (int r = 0; r < 8; ++r) {
            float4 v = ax4[r * 50 + kh];  // (a_k, x_k, a_{k+1}, x_{k+1}) wave-broadcast
            acc[r][0] += v.x * wl0.x + v.y * wr0.x + v.z * wl1.x + v.w * wr1.x;
            acc[r][1] += v.x * wl0.y + v.y * wr0.y + v.z * wl1.y + v.w * wr1.y;
            acc[r][2] += v.x * wl0.z + v.y * wr0.z + v.z * wl1.z + v.w * wr1.z;
            acc[r][3] += v.x * wl0.w + v.y * wr0.w + v.z * wl1.w + v.w * wr1.w;
        }
    }

    float4 b = *(const float4*)(b1l + j4);
    #pragma unroll
    for (int r = 0; r < 8; ++r) {
        int row = i0 + rgrp * 8 + r;
        float4 o;
        o.x = fmaxf(acc[r][0] + b.x, 0.f);
        o.y = fmaxf(acc[r][1] + b.y, 0.f);
        o.z = fmaxf(acc[r][2] + b.z, 0.f);
        o.w = fmaxf(acc[r][3] + b.w, 0.f);
        *(float4*)(h + row * HID + j4) = o;
    }
}

// ---------------------------------------------------------------------------
// Fused layer 2: per-wave aggregation (float4/lane over 256ch) -> LDS ->
// GEMM (lanes 0..46 = output cols) + bias + wave-level log_softmax.
// ---------------------------------------------------------------------------
__global__ __launch_bounds__(256) void l2_fused_kernel(
    const float* __restrict__ h, const int* __restrict__ ell2,
    const int* __restrict__ deg2,
    const float* __restrict__ W2l, const float* __restrict__ b2l,
    const float* __restrict__ W2r, float* __restrict__ out) {
    __shared__ float sa[4][HID];
    __shared__ float sh_[4][HID];
    int w = threadIdx.x >> 6;
    int lane = threadIdx.x & 63;
    int row = (blockIdx.x << 2) + w;

    int nd = deg2[row];
    int n = (nd < S2) ? nd : S2;
    const int* rp = ell2 + row * S2;
    float4 acc4 = {0.f, 0.f, 0.f, 0.f};
    int e = 0;
    for (; e + 1 < n; e += 2) {
        int s0 = rp[e], s1 = rp[e + 1];
        float4 v0 = ((const float4*)(h + s0 * HID))[lane];
        float4 v1 = ((const float4*)(h + s1 * HID))[lane];
        acc4.x += v0.x + v1.x; acc4.y += v0.y + v1.y;
        acc4.z += v0.z + v1.z; acc4.w += v0.w + v1.w;
    }
    if (e < n) {
        int s0 = rp[e];
        float4 v0 = ((const float4*)(h + s0 * HID))[lane];
        acc4.x += v0.x; acc4.y += v0.y; acc4.z += v0.z; acc4.w += v0.w;
    }
    float inv = 1.0f / (float)(nd > 0 ? nd : 1);
    float4 am = {acc4.x * inv, acc4.y * inv, acc4.z * inv, acc4.w * inv};
    ((float4*)&sa[w][0])[lane] = am;
    ((float4*)&sh_[w][0])[lane] = ((const float4*)(h + row * HID))[lane];
    __syncthreads();

    int j = lane;
    int jj = (j < OUT_C) ? j : (OUT_C - 1);
    float acc = 0.f;
    for (int k = 0; k < HID; k += 4) {
        float4 av = *(const float4*)&sa[w][k];   // same-addr broadcast
        float4 hv = *(const float4*)&sh_[w][k];
        acc += av.x * W2l[(k + 0) * OUT_C + jj] + hv.x * W2r[(k + 0) * OUT_C + jj];
        acc += av.y * W2l[(k + 1) * OUT_C + jj] + hv.y * W2r[(k + 1) * OUT_C + jj];
        acc += av.z * W2l[(k + 2) * OUT_C + jj] + hv.z * W2r[(k + 2) * OUT_C + jj];
        acc += av.w * W2l[(k + 3) * OUT_C + jj] + hv.w * W2r[(k + 3) * OUT_C + jj];
    }
    float v = acc + b2l[jj];
    float vm = (j < OUT_C) ? v : -__builtin_huge_valf();
    #pragma unroll
    for (int s = 32; s > 0; s >>= 1) vm = fmaxf(vm, __shfl_xor(vm, s));
    float ex = (j < OUT_C) ? __expf(v - vm) : 0.f;
    #pragma unroll
    for (int s = 32; s > 0; s >>= 1) ex += __shfl_xor(ex, s);
    if (j < OUT_C) out[row * OUT_C + j] = v - vm - __logf(ex);
}

// ---------------------------------------------------------------------------
extern "C" void kernel_launch(void* const* d_in, const int* in_sizes, int n_in,
                              void* d_out, int out_size, void* d_ws, size_t ws_size,
                              hipStream_t stream) {
    const float* x   = (const float*)d_in[0];
    const float* W1l = (const float*)d_in[1];
    const float* b1l = (const float*)d_in[2];
    const float* W1r = (const float*)d_in[3];
    const float* W2l = (const float*)d_in[4];
    const float* b2l = (const float*)d_in[5];
    const float* W2r = (const float*)d_in[6];
    const int* src1  = (const int*)d_in[7];
    const int* dst1  = (const int*)d_in[8];
    const int* src2  = (const int*)d_in[9];
    const int* dst2  = (const int*)d_in[10];
    float* out = (float*)d_out;

    char* ws = (char*)d_ws;
    size_t off = 0;
    auto alloc = [&](size_t bytes) {
        off = (off + 255) & ~(size_t)255;
        void* p = ws + off;
        off += bytes;
        return p;
    };

    int* deg1 = (int*)alloc(N1 * sizeof(int));       // contiguous with deg2
    int* deg2 = (int*)alloc(N2 * sizeof(int));
    int* ell1 = (int*)alloc((size_t)N1 * S1 * sizeof(int));
    int* ell2 = (int*)alloc((size_t)N2 * S2 * sizeof(int));
    float* aggm1 = (float*)alloc((size_t)N1 * IN_C * sizeof(float));
    float* h     = (float*)alloc((size_t)N1 * HID * sizeof(float));

    hipMemsetAsync(deg1, 0, (N1 + N2) * sizeof(int), stream);

    build_kernel<<<(E1 / 2 + E2 / 2) / 256, 256, 0, stream>>>(
        src1, dst1, src2, dst2, deg1, ell1, deg2, ell2);
    agg1_kernel<<<N1 / 4, 256, 0, stream>>>(x, ell1, deg1, aggm1);
    gemm1_kernel<<<N1 / 32, 256, 0, stream>>>(aggm1, x, W1l, b1l, W1r, h);
    l2_fused_kernel<<<N2 / 4, 256, 0, stream>>>(h, ell2, deg2, W2l, b2l, W2r, out);
}

// Round 5
// 670.281 us; speedup vs baseline: 1.1204x; 1.0594x over previous
//
#include <hip/hip_runtime.h>
#include <math.h>

#define N0 1000000
#define N1 40960
#define N2 4096
#define E1 1024000
#define E2 40960
#define IN_C 100
#define HID 256
#define OUT_C 47
#define S1 128   // ELL stride layer1 (deg ~Poisson(25))
#define S2 64    // ELL stride layer2 (deg ~Poisson(10))
#define KCAT 224          // padded K for [agg|x] (200 -> 224 = 7*32)
#define KSTEPS 7          // 224/32
#define LDSTR 232         // LDS row stride in bf16 (padded: 464B, bank-safe)

typedef __attribute__((ext_vector_type(8))) short short8;
typedef __attribute__((ext_vector_type(4))) float float4v;

// fp32 -> bf16 RNE (finite inputs)
__device__ inline unsigned short f2bf(float f) {
    union { float f; unsigned u; } v; v.f = f;
    unsigned r = v.u + 0x7FFF + ((v.u >> 16) & 1);
    return (unsigned short)(r >> 16);
}

// ---------------------------------------------------------------------------
// Single-pass ELL build (2 edges/thread, int2) + W-pack (blocks >= EDGE_BLKS).
// packed[(nt*7+ks)*512 + lane*8 + j] = bf16( Wcat[ks*32 + (lane>>4)*8 + j][nt*16 + (lane&15)] )
// Wcat[k][n] = k<100 ? W1l[k][n] : k<200 ? W1r[k-100][n] : 0
// ---------------------------------------------------------------------------
#define EDGE_BLKS ((E1 / 2 + E2 / 2) / 256)   // 2080
#define PACK_BLKS 28                          // 7168 threads, 16*7*64 chunks
__global__ __launch_bounds__(256) void build_kernel(
    const int* __restrict__ src1, const int* __restrict__ dst1,
    const int* __restrict__ src2, const int* __restrict__ dst2,
    int* __restrict__ deg1, int* __restrict__ ell1,
    int* __restrict__ deg2, int* __restrict__ ell2,
    const float* __restrict__ W1l, const float* __restrict__ W1r,
    unsigned short* __restrict__ packedW) {
    if (blockIdx.x >= EDGE_BLKS) {
        int t = (blockIdx.x - EDGE_BLKS) * 256 + threadIdx.x;  // < 7168
        int nt = t / 448;
        int rem = t - nt * 448;
        int ks = rem >> 6;
        int lane = rem & 63;
        int n = nt * 16 + (lane & 15);
        int kbase = ks * 32 + (lane >> 4) * 8;
        unsigned short* wp = packedW + (size_t)(nt * 7 + ks) * 512 + lane * 8;
        #pragma unroll
        for (int j = 0; j < 8; ++j) {
            int k = kbase + j;
            float v = (k < 100) ? W1l[k * HID + n]
                    : (k < 200) ? W1r[(k - 100) * HID + n] : 0.f;
            wp[j] = f2bf(v);
        }
        return;
    }
    int gid = blockIdx.x * 256 + threadIdx.x;
    if (gid < E1 / 2) {
        int2 s = ((const int2*)src1)[gid];
        int2 d = ((const int2*)dst1)[gid];
        int slot0 = atomicAdd(&deg1[d.x], 1);
        if (slot0 < S1) ell1[d.x * S1 + slot0] = s.x;
        int slot1 = atomicAdd(&deg1[d.y], 1);
        if (slot1 < S1) ell1[d.y * S1 + slot1] = s.y;
    } else {
        int p = gid - E1 / 2;
        int2 s = ((const int2*)src2)[p];
        int2 d = ((const int2*)dst2)[p];
        int slot0 = atomicAdd(&deg2[d.x], 1);
        if (slot0 < S2) ell2[d.x * S2 + slot0] = s.x;
        int slot1 = atomicAdd(&deg2[d.y], 1);
        if (slot1 < S2) ell2[d.y * S2 + slot1] = s.y;
    }
}

// ---------------------------------------------------------------------------
// Layer 1 mean-aggregation: one wave per dst node; lane l<50 reads float2 #l
// of each 400B source row (one coalesced load per edge); 8-edge unroll.
// ---------------------------------------------------------------------------
__global__ __launch_bounds__(256) void agg1_kernel(
    const float* __restrict__ x, const int* __restrict__ ell1,
    const int* __restrict__ deg1, float* __restrict__ aggm1) {
    int d = (blockIdx.x << 2) + (threadIdx.x >> 6);
    int lane = threadIdx.x & 63;
    int l2 = (lane < 50) ? lane : 49;
    int nd = deg1[d];
    int n = (nd < S1) ? nd : S1;
    const int* rp = ell1 + d * S1;

    float x0 = 0.f, y0 = 0.f, x1 = 0.f, y1 = 0.f;
    float x2 = 0.f, y2 = 0.f, x3 = 0.f, y3 = 0.f;
    int e = 0;
    for (; e + 7 < n; e += 8) {
        int s0 = rp[e],     s1 = rp[e + 1], s2 = rp[e + 2], s3 = rp[e + 3];
        int s4 = rp[e + 4], s5 = rp[e + 5], s6 = rp[e + 6], s7 = rp[e + 7];
        float2 v0 = ((const float2*)(x + s0 * IN_C))[l2];
        float2 v1 = ((const float2*)(x + s1 * IN_C))[l2];
        float2 v2 = ((const float2*)(x + s2 * IN_C))[l2];
        float2 v3 = ((const float2*)(x + s3 * IN_C))[l2];
        float2 v4 = ((const float2*)(x + s4 * IN_C))[l2];
        float2 v5 = ((const float2*)(x + s5 * IN_C))[l2];
        float2 v6 = ((const float2*)(x + s6 * IN_C))[l2];
        float2 v7 = ((const float2*)(x + s7 * IN_C))[l2];
        x0 += v0.x + v4.x; y0 += v0.y + v4.y;
        x1 += v1.x + v5.x; y1 += v1.y + v5.y;
        x2 += v2.x + v6.x; y2 += v2.y + v6.y;
        x3 += v3.x + v7.x; y3 += v3.y + v7.y;
    }
    for (; e + 1 < n; e += 2) {
        int s0 = rp[e], s1 = rp[e + 1];
        float2 v0 = ((const float2*)(x + s0 * IN_C))[l2];
        float2 v1 = ((const float2*)(x + s1 * IN_C))[l2];
        x0 += v0.x; y0 += v0.y;
        x1 += v1.x; y1 += v1.y;
    }
    if (e < n) {
        float2 v0 = ((const float2*)(x + rp[e] * IN_C))[l2];
        x0 += v0.x; y0 += v0.y;
    }
    float sx = (x0 + x1) + (x2 + x3);
    float sy = (y0 + y1) + (y2 + y3);
    float inv = 1.0f / (float)(nd > 0 ? nd : 1);
    if (lane < 50) {
        float2 o = {sx * inv, sy * inv};
        ((float2*)(aggm1 + d * IN_C))[lane] = o;
    }
}

// ---------------------------------------------------------------------------
// Layer 1 GEMM via bf16 MFMA:  h = relu([agg|x] . [W1l;W1r] + b1l)
// Block: 32 rows; A staged bf16 in LDS (stride 232); B from packedW (coalesced).
// Wave w: col-tiles nt = w*4..w*4+3, row-tiles rt=0,1; acc = 8 x float4.
// mfma_f32_16x16x32_bf16: A[m=lane&15][k=quad*8+j]; D: col=lane&15, row=quad*4+reg.
// ---------------------------------------------------------------------------
__global__ __launch_bounds__(256) void gemm1_kernel(
    const float* __restrict__ aggm1, const float* __restrict__ x,
    const unsigned short* __restrict__ packedW, const float* __restrict__ b1l,
    float* __restrict__ h) {
    __shared__ short As[32 * LDSTR];   // 14,848 B
    int tid = threadIdx.x;
    int i0 = blockIdx.x * 32;

    // stage agg -> k[0..99]
    const float2* ag2 = (const float2*)(aggm1 + (size_t)i0 * IN_C);
    for (int idx = tid; idx < 32 * 50; idx += 256) {
        int r = idx / 50;
        int p = idx - r * 50;
        float2 v = ag2[idx];
        short2 o = {(short)f2bf(v.x), (short)f2bf(v.y)};
        *(short2*)(As + r * LDSTR + 2 * p) = o;
    }
    // stage x_self -> k[100..199]
    const float2* xs2 = (const float2*)(x + (size_t)i0 * IN_C);
    for (int idx = tid; idx < 32 * 50; idx += 256) {
        int r = idx / 50;
        int p = idx - r * 50;
        float2 v = xs2[idx];
        short2 o = {(short)f2bf(v.x), (short)f2bf(v.y)};
        *(short2*)(As + r * LDSTR + 100 + 2 * p) = o;
    }
    // zero pad k[200..223]
    for (int idx = tid; idx < 32 * 12; idx += 256) {
        int r = idx / 12;
        int p = idx - r * 12;
        short2 z = {0, 0};
        *(short2*)(As + r * LDSTR + 200 + 2 * p) = z;
    }
    __syncthreads();

    int lane = tid & 63;
    int w = tid >> 6;
    int quad = lane >> 4;
    int m = lane & 15;

    float4v acc[2][4];
    #pragma unroll
    for (int rt = 0; rt < 2; ++rt)
        #pragma unroll
        for (int c = 0; c < 4; ++c) acc[rt][c] = (float4v){0.f, 0.f, 0.f, 0.f};

    #pragma unroll
    for (int ks = 0; ks < KSTEPS; ++ks) {
        int ko = ks * 32 + quad * 8;
        short8 a0 = *(const short8*)(As + (0 * 16 + m) * LDSTR + ko);
        short8 a1 = *(const short8*)(As + (1 * 16 + m) * LDSTR + ko);
        #pragma unroll
        for (int c = 0; c < 4; ++c) {
            int nt = w * 4 + c;
            short8 b = *(const short8*)(packedW + (size_t)(nt * 7 + ks) * 512 + lane * 8);
            acc[0][c] = __builtin_amdgcn_mfma_f32_16x16x32_bf16(a0, b, acc[0][c], 0, 0, 0);
            acc[1][c] = __builtin_amdgcn_mfma_f32_16x16x32_bf16(a1, b, acc[1][c], 0, 0, 0);
        }
    }

    // epilogue: bias + relu, D layout col=lane&15 row=quad*4+reg
    #pragma unroll
    for (int c = 0; c < 4; ++c) {
        int col = (w * 4 + c) * 16 + m;
        float bv = b1l[col];
        #pragma unroll
        for (int rt = 0; rt < 2; ++rt) {
            int rbase = i0 + rt * 16 + quad * 4;
            #pragma unroll
            for (int reg = 0; reg < 4; ++reg) {
                float v = acc[rt][c][reg] + bv;
                h[(size_t)(rbase + reg) * HID + col] = fmaxf(v, 0.f);
            }
        }
    }
}

// ---------------------------------------------------------------------------
// Fused layer 2: per-wave aggregation (float4/lane over 256ch) -> LDS ->
// GEMM (lanes 0..46 = output cols) + bias + wave-level log_softmax.
// ---------------------------------------------------------------------------
__global__ __launch_bounds__(256) void l2_fused_kernel(
    const float* __restrict__ h, const int* __restrict__ ell2,
    const int* __restrict__ deg2,
    const float* __restrict__ W2l, const float* __restrict__ b2l,
    const float* __restrict__ W2r, float* __restrict__ out) {
    __shared__ float sa[4][HID];
    __shared__ float sh_[4][HID];
    int w = threadIdx.x >> 6;
    int lane = threadIdx.x & 63;
    int row = (blockIdx.x << 2) + w;

    int nd = deg2[row];
    int n = (nd < S2) ? nd : S2;
    const int* rp = ell2 + row * S2;
    float4 acc4 = {0.f, 0.f, 0.f, 0.f};
    int e = 0;
    for (; e + 1 < n; e += 2) {
        int s0 = rp[e], s1 = rp[e + 1];
        float4 v0 = ((const float4*)(h + s0 * HID))[lane];
        float4 v1 = ((const float4*)(h + s1 * HID))[lane];
        acc4.x += v0.x + v1.x; acc4.y += v0.y + v1.y;
        acc4.z += v0.z + v1.z; acc4.w += v0.w + v1.w;
    }
    if (e < n) {
        int s0 = rp[e];
        float4 v0 = ((const float4*)(h + s0 * HID))[lane];
        acc4.x += v0.x; acc4.y += v0.y; acc4.z += v0.z; acc4.w += v0.w;
    }
    float inv = 1.0f / (float)(nd > 0 ? nd : 1);
    float4 am = {acc4.x * inv, acc4.y * inv, acc4.z * inv, acc4.w * inv};
    ((float4*)&sa[w][0])[lane] = am;
    ((float4*)&sh_[w][0])[lane] = ((const float4*)(h + row * HID))[lane];
    __syncthreads();

    int j = lane;
    int jj = (j < OUT_C) ? j : (OUT_C - 1);
    float acc = 0.f;
    for (int k = 0; k < HID; k += 4) {
        float4 av = *(const float4*)&sa[w][k];   // same-addr broadcast
        float4 hv = *(const float4*)&sh_[w][k];
        acc += av.x * W2l[(k + 0) * OUT_C + jj] + hv.x * W2r[(k + 0) * OUT_C + jj];
        acc += av.y * W2l[(k + 1) * OUT_C + jj] + hv.y * W2r[(k + 1) * OUT_C + jj];
        acc += av.z * W2l[(k + 2) * OUT_C + jj] + hv.z * W2r[(k + 2) * OUT_C + jj];
        acc += av.w * W2l[(k + 3) * OUT_C + jj] + hv.w * W2r[(k + 3) * OUT_C + jj];
    }
    float v = acc + b2l[jj];
    float vm = (j < OUT_C) ? v : -__builtin_huge_valf();
    #pragma unroll
    for (int s = 32; s > 0; s >>= 1) vm = fmaxf(vm, __shfl_xor(vm, s));
    float ex = (j < OUT_C) ? __expf(v - vm) : 0.f;
    #pragma unroll
    for (int s = 32; s > 0; s >>= 1) ex += __shfl_xor(ex, s);
    if (j < OUT_C) out[row * OUT_C + j] = v - vm - __logf(ex);
}

// ---------------------------------------------------------------------------
extern "C" void kernel_launch(void* const* d_in, const int* in_sizes, int n_in,
                              void* d_out, int out_size, void* d_ws, size_t ws_size,
                              hipStream_t stream) {
    const float* x   = (const float*)d_in[0];
    const float* W1l = (const float*)d_in[1];
    const float* b1l = (const float*)d_in[2];
    const float* W1r = (const float*)d_in[3];
    const float* W2l = (const float*)d_in[4];
    const float* b2l = (const float*)d_in[5];
    const float* W2r = (const float*)d_in[6];
    const int* src1  = (const int*)d_in[7];
    const int* dst1  = (const int*)d_in[8];
    const int* src2  = (const int*)d_in[9];
    const int* dst2  = (const int*)d_in[10];
    float* out = (float*)d_out;

    char* ws = (char*)d_ws;
    size_t off = 0;
    auto alloc = [&](size_t bytes) {
        off = (off + 255) & ~(size_t)255;
        void* p = ws + off;
        off += bytes;
        return p;
    };

    int* deg1 = (int*)alloc(N1 * sizeof(int));       // contiguous with deg2
    int* deg2 = (int*)alloc(N2 * sizeof(int));
    int* ell1 = (int*)alloc((size_t)N1 * S1 * sizeof(int));
    int* ell2 = (int*)alloc((size_t)N2 * S2 * sizeof(int));
    float* aggm1 = (float*)alloc((size_t)N1 * IN_C * sizeof(float));
    float* h     = (float*)alloc((size_t)N1 * HID * sizeof(float));
    unsigned short* packedW = (unsigned short*)alloc((size_t)16 * 7 * 512 * sizeof(unsigned short));

    hipMemsetAsync(deg1, 0, (N1 + N2) * sizeof(int), stream);

    build_kernel<<<EDGE_BLKS + PACK_BLKS, 256, 0, stream>>>(
        src1, dst1, src2, dst2, deg1, ell1, deg2, ell2, W1l, W1r, packedW);
    agg1_kernel<<<N1 / 4, 256, 0, stream>>>(x, ell1, deg1, aggm1);
    gemm1_kernel<<<N1 / 32, 256, 0, stream>>>(aggm1, x, packedW, b1l, h);
    l2_fused_kernel<<<N2 / 4, 256, 0, stream>>>(h, ell2, deg2, W2l, b2l, W2r, out);
}